// Round 17
// baseline (4303.628 us; speedup 1.0000x reference)
//
#include <hip/hip_runtime.h>
#include <hip/hip_bf16.h>

#define S_LEN   512
#define BATCH   64
#define DH      512
#define KDIM    1024      // 2*DH (concat [h, x])
#define NCOLS   64        // 4 gates * 16 units per WG
#define WGL     128       // WGs per layer
#define NWG     256
#define THREADS 256
#define NSLOT   4         // h rotation depth
#define FLAG_STRIDE 32    // uints: one flag per 128-B line
#define W_LDS_BYTES (NCOLS * KDIM * 2)           // 131072 weights
#define P_LDS_BYTES (16 * 64 * 16)               // 16384 partials
#define LDS_BYTES   (W_LDS_BYTES + P_LDS_BYTES)  // 147456 <= 160K

// ws layout (byte offsets):
//   0       : h0 tagged u32 [4][64][512]  (512 KB)   (h_bf16<<16)|epoch
//   524288  : h1 tagged u32 [4][64][512]  (512 KB)
//   1048576 : flags[256*32] u32 (only L1's 128 used: read-completion for WAR)
//   1081344 : seq_bf16 ushort [512][64][512]  (32 MB)
#define WS_H0_B  0
#define WS_H1_B  524288
#define WS_BAR_B 1048576
#define WS_XB_B  1081344

typedef __attribute__((ext_vector_type(8))) unsigned short u16x8;
typedef __attribute__((ext_vector_type(8))) __bf16         bf16x8;
typedef __attribute__((ext_vector_type(4))) float          f32x4;
typedef __attribute__((ext_vector_type(4))) unsigned       u32x4;

__device__ __forceinline__ unsigned short f2bf(float f) {
    unsigned u = __float_as_uint(f);
    return (unsigned short)((u + 0x7fffu + ((u >> 16) & 1u)) >> 16);   // RNE
}
__device__ __forceinline__ float sigmoid_f(float x) { return 1.f / (1.f + __expf(-x)); }
__device__ __forceinline__ float tanh_f(float x) {
    float e = __expf(2.f * x);
    return 1.f - 2.f / (e + 1.f);
}
__device__ __forceinline__ f32x4 mfma16(bf16x8 a, bf16x8 b, f32x4 c) {
    return __builtin_amdgcn_mfma_f32_16x16x32_bf16(a, b, c, 0, 0, 0);
}
// 32-bit agent-scope relaxed atomics (proven instruction class, compiler-tracked).
__device__ __forceinline__ unsigned ld_coh32(const unsigned* p) {
    return __hip_atomic_load(p, __ATOMIC_RELAXED, __HIP_MEMORY_SCOPE_AGENT);
}
__device__ __forceinline__ void st_coh32(unsigned* p, unsigned v) {
    __hip_atomic_store(p, v, __ATOMIC_RELAXED, __HIP_MEMORY_SCOPE_AGENT);
}

// Poll 32 tagged dwords (4 chunks x 8) until ALL lanes see tag == need.
// Detect and load are the SAME round trip; stale slot shows tag need-4 -> retry.
#define POLL_TAGGED(base_, need_, arr_) do {                                   \
    const unsigned nd_ = (unsigned)(need_);                                    \
    for (;;) {                                                                 \
        unsigned ok_ = 1u;                                                     \
        _Pragma("unroll")                                                      \
        for (int c_ = 0; c_ < 4; ++c_) {                                       \
            _Pragma("unroll")                                                  \
            for (int j_ = 0; j_ < 8; ++j_) {                                   \
                unsigned v_ = ld_coh32((base_) + c_ * 32 + j_);                \
                (arr_)[c_ * 8 + j_] = v_;                                      \
                ok_ &= (unsigned)((v_ & 0xffffu) == nd_);                      \
            }                                                                  \
        }                                                                      \
        if (__all((int)ok_)) break;                                            \
    }                                                                          \
} while (0)

#define LDWB(off_) __builtin_bit_cast(bf16x8, *(const u16x8*)((const char*)wlds + (off_)))

__global__ void lstm_init(const float* __restrict__ seq,
                          const float* __restrict__ h_init,
                          unsigned char* __restrict__ wsb) {
    const int gid = blockIdx.x * blockDim.x + threadIdx.x;
    unsigned* flags = (unsigned*)(wsb + WS_BAR_B);
    unsigned* h0dw  = (unsigned*)(wsb + WS_H0_B);
    unsigned* h1dw  = (unsigned*)(wsb + WS_H1_B);
    unsigned short* xb = (unsigned short*)(wsb + WS_XB_B);

    if (gid < NWG) flags[gid * FLAG_STRIDE] = 0;
    // Re-tag ALL h slots every launch: graph replays leave stale tags from the
    // previous run (d_ws is not re-poisoned), which would corrupt/deadlock the
    // tag protocol. Live slots get init data; others get sentinel 0xFFFFFFFF.
    if (gid < NSLOT * BATCH * DH) {
        const int slot = gid >> 15;              // / (BATCH*DH)
        const int idx  = gid & (BATCH * DH - 1);
        h0dw[gid] = (slot == 0) ? (((unsigned)f2bf(h_init[idx]) << 16) | 0u)
                                : 0xFFFFFFFFu;
        h1dw[gid] = (slot == 1) ? (((unsigned)f2bf(h_init[(size_t)BATCH * DH + idx]) << 16) | 1u)
                                : 0xFFFFFFFFu;
    }
    // seq fp32 -> bf16 pre-pass
    const size_t total = (size_t)S_LEN * BATCH * DH;
    const size_t nthr  = (size_t)gridDim.x * blockDim.x;
    for (size_t i = (size_t)gid * 4; i < total; i += nthr * 4) {
        float4 v = *(const float4*)(seq + i);
        unsigned d0 = (unsigned)f2bf(v.x) | ((unsigned)f2bf(v.y) << 16);
        unsigned d1 = (unsigned)f2bf(v.z) | ((unsigned)f2bf(v.w) << 16);
        *(unsigned*)(xb + i)     = d0;
        *(unsigned*)(xb + i + 2) = d1;
    }
}

__global__ __launch_bounds__(THREADS, 1)
void lstm_main(const float* __restrict__ seq,
               const float* __restrict__ Wf, const float* __restrict__ Bf,
               const float* __restrict__ Wi, const float* __restrict__ Bi,
               const float* __restrict__ Wc, const float* __restrict__ Bc,
               const float* __restrict__ Wo, const float* __restrict__ Bo,
               float* __restrict__ out, unsigned char* __restrict__ wsb)
{
    extern __shared__ unsigned short wlds[];   // weights [64][1024] bf16 swizzled
    float* plds = (float*)((char*)wlds + W_LDS_BYTES);   // [16 frag][64 lane][4] f32

    const int wg    = blockIdx.x;
    const int layer = wg >> 7;               // 0..1
    const int rid   = wg & (WGL - 1);        // 0..127
    const int us    = rid >> 2;              // unit-slice 0..31
    const int bg    = rid & 3;               // batch-group 0..3
    const int jbase = us * 16;
    const int bbase = bg * 16;
    const int tid   = threadIdx.x;
    const int lane  = tid & 63;
    const int wave  = tid >> 6;

    unsigned* h0dw  = (unsigned*)(wsb + WS_H0_B);
    unsigned* h1dw  = (unsigned*)(wsb + WS_H1_B);
    unsigned* flags = (unsigned*)(wsb + WS_BAR_B);
    unsigned short* xb = (unsigned short*)(wsb + WS_XB_B);

    // ---- stage this WG's weight slice into LDS (bf16, swizzled), once ----
    {
        const size_t woff = (size_t)layer * KDIM * DH;
        const float* Wg[4] = { Wf + woff, Wi + woff, Wc + woff, Wo + woff };
        for (int idx = tid; idx < NCOLS * KDIM; idx += THREADS) {
            int mcol = idx & (NCOLS - 1);          // gate*16 + unit
            int k    = idx >> 6;
            float w  = Wg[mcol >> 4][(size_t)k * DH + jbase + (mcol & 15)];
            unsigned byte = ((unsigned)mcol * 2048u + (unsigned)k * 2u)
                          ^ (((unsigned)mcol & 7u) << 4);
            wlds[byte >> 1] = f2bf(w);
        }
    }

    // MFMA geometry: A=weights (M=16 units), B=acts (N=16 batch).
    const int ln  = lane & 15;
    const int lq  = lane >> 4;
    const int klo = lq * 8;
    const unsigned sw  = ((unsigned)(lane & 7)) << 4;
    const unsigned wbF = (0u * 16 + (unsigned)ln) * 2048u;
    const unsigned wbI = (1u * 16 + (unsigned)ln) * 2048u;
    const unsigned wbC = (2u * 16 + (unsigned)ln) * 2048u;
    const unsigned wbO = (3u * 16 + (unsigned)ln) * 2048u;

    // per-thread output cell: unit ul, batch bl
    const int ul = tid & 15;
    const int bl = tid >> 4;
    const int lidx = (ul >> 2) * 16 + bl;
    const int ridx = ul & 3;
    const float bF = Bf[layer * DH + jbase + ul];
    const float bI = Bi[layer * DH + jbase + ul];
    const float bC = Bc[layer * DH + jbase + ul];
    const float bO = Bo[layer * DH + jbase + ul];

    // WAR flag pointer (L0 only): 32 same-bg L1 flags (read-completion), 2-slack.
    const unsigned* pfW = &flags[(128 + (lane & 31) * 4 + bg) * FLAG_STRIDE];
    __syncthreads();

    float cs = 0.f;

    for (int it = 0; it <= S_LEN; ++it) {
        const bool active = layer ? (it >= 1) : (it < S_LEN);
        const int  t      = layer ? it - 1 : it;

        if (active) {
            const int par = it & (NSLOT - 1);
            f32x4 eF = {0,0,0,0}, eI = {0,0,0,0}, eC = {0,0,0,0}, eO = {0,0,0,0};
            f32x4 oF = {0,0,0,0}, oI = {0,0,0,0}, oC = {0,0,0,0}, oO = {0,0,0,0};
            unsigned ah[32];

            #define XMFMA(c_, av_) do {                                            \
                const unsigned kb = ((unsigned)(16 + wave * 4 + (c_)) * 64u        \
                                     + (unsigned)klo * 2u) ^ sw;                   \
                bf16x8 wFx = LDWB(wbF + kb), wIx = LDWB(wbI + kb);                 \
                bf16x8 wCx = LDWB(wbC + kb), wOx = LDWB(wbO + kb);                 \
                if ((c_) & 1) {                                                    \
                    oF = mfma16(wFx, (av_), oF); oI = mfma16(wIx, (av_), oI);      \
                    oC = mfma16(wCx, (av_), oC); oO = mfma16(wOx, (av_), oO);      \
                } else {                                                           \
                    eF = mfma16(wFx, (av_), eF); eI = mfma16(wIx, (av_), eI);      \
                    eC = mfma16(wCx, (av_), eC); eO = mfma16(wOx, (av_), eO);      \
                } } while (0)
            #define UNPACK8(arr_, c_) ({                                           \
                u32x4 q_;                                                          \
                q_[0] = ((arr_)[(c_)*8+0] >> 16) | ((arr_)[(c_)*8+1] & 0xffff0000u); \
                q_[1] = ((arr_)[(c_)*8+2] >> 16) | ((arr_)[(c_)*8+3] & 0xffff0000u); \
                q_[2] = ((arr_)[(c_)*8+4] >> 16) | ((arr_)[(c_)*8+5] & 0xffff0000u); \
                q_[3] = ((arr_)[(c_)*8+6] >> 16) | ((arr_)[(c_)*8+7] & 0xffff0000u); \
                __builtin_bit_cast(bf16x8, q_); })

            const size_t rowoff = (size_t)par * BATCH * DH
                                + (size_t)(bbase + ln) * DH + wave * 128 + klo;

            if (!layer) {
                // WAR back-edge (2-slack, rarely blocks): L1 read epoch it-3 done
                {
                    int ni = it - 2; if (ni < 0) ni = 0;
                    unsigned v = ld_coh32(pfW);
                    while (!__all((int)(v >= (unsigned)ni)))
                        v = ld_coh32(pfW);
                }
                // x-half from seq_bf16 (cached, flag-free) pre-poll
                const unsigned short* xrow = xb
                    + ((size_t)t * BATCH + bbase + ln) * DH + klo;
                #pragma unroll
                for (int c = 0; c < 4; ++c) {
                    u16x8 xv = *(const u16x8*)(xrow + (wave * 4 + c) * 32);
                    bf16x8 av = __builtin_bit_cast(bf16x8, xv);
                    XMFMA(c, av);
                }
                // tagged h0: detect+load fused, single RT (the tight edge)
                POLL_TAGGED(h0dw + rowoff, it, ah);
                __builtin_amdgcn_sched_barrier(0);
            } else {
                // x = tagged h0 (L0 runs ahead -> expected ready on first pass)
                unsigned ax[32];
                POLL_TAGGED(h0dw + rowoff, it, ax);
                __builtin_amdgcn_sched_barrier(0);
                #pragma unroll
                for (int c = 0; c < 4; ++c) {
                    bf16x8 av = UNPACK8(ax, c);
                    XMFMA(c, av);
                }
                // tagged h1 self-dep (the tight edge)
                POLL_TAGGED(h1dw + rowoff, it, ah);
                __builtin_amdgcn_sched_barrier(0);
            }

            // h-MFMAs (chunks s = wave*4+c)
            #pragma unroll
            for (int c = 0; c < 4; ++c) {
                bf16x8 av = UNPACK8(ah, c);
                const unsigned kb = ((unsigned)(wave * 4 + c) * 64u
                                     + (unsigned)klo * 2u) ^ sw;
                bf16x8 wFh = LDWB(wbF + kb), wIh = LDWB(wbI + kb);
                bf16x8 wCh = LDWB(wbC + kb), wOh = LDWB(wbO + kb);
                if (c & 1) {
                    oF = mfma16(wFh, av, oF); oI = mfma16(wIh, av, oI);
                    oC = mfma16(wCh, av, oC); oO = mfma16(wOh, av, oO);
                } else {
                    eF = mfma16(wFh, av, eF); eI = mfma16(wIh, av, eI);
                    eC = mfma16(wCh, av, eC); eO = mfma16(wOh, av, eO);
                }
            }
            #undef XMFMA
            #undef UNPACK8
            f32x4 pF = eF + oF, pI = eI + oI, pC = eC + oC, pO = eO + oO;

            // ---- cross-wave K-reduction via LDS ----
            f32x4* pv = (f32x4*)plds;
            pv[(wave * 4 + 0) * 64 + lane] = pF;
            pv[(wave * 4 + 1) * 64 + lane] = pI;
            pv[(wave * 4 + 2) * 64 + lane] = pC;
            pv[(wave * 4 + 3) * 64 + lane] = pO;
            __syncthreads();
            // L1 publishes read-completion (all waves' x loads consumed by now)
            if (layer && tid == 0)
                st_coh32(&flags[wg * FLAG_STRIDE], (unsigned)(it + 1));

            float sF = 0.f, sI = 0.f, sC = 0.f, sO = 0.f;
            #pragma unroll
            for (int w = 0; w < 4; ++w) {
                sF += plds[((w * 4 + 0) * 64 + lidx) * 4 + ridx];
                sI += plds[((w * 4 + 1) * 64 + lidx) * 4 + ridx];
                sC += plds[((w * 4 + 2) * 64 + lidx) * 4 + ridx];
                sO += plds[((w * 4 + 3) * 64 + lidx) * 4 + ridx];
            }

            const float fg = sigmoid_f(sF + bF);
            const float ig = sigmoid_f(sI + bI);
            const float ct = tanh_f  (sC + bC);
            const float og = sigmoid_f(sO + bO);
            const float cn = fg * cs + ig * ct;
            cs = cn;
            const float hv = og * tanh_f(cn);

            // ---- tagged h-store: data+epoch in one dword, per-thread visible ----
            const int npar = (it + 1) & (NSLOT - 1);
            {
                unsigned dw = ((unsigned)f2bf(hv) << 16) | (unsigned)(it + 1);
                unsigned* dst = (layer ? h1dw : h0dw)
                    + (size_t)npar * BATCH * DH + (size_t)(bbase + bl) * DH
                    + jbase + ul;
                st_coh32(dst, dw);
            }

            if (layer) {
                __builtin_nontemporal_store(hv,
                    out + ((size_t)t * BATCH + bbase + bl) * DH + jbase + ul);
                if (t == S_LEN - 1)
                    __builtin_nontemporal_store(hv,
                        out + (size_t)S_LEN * BATCH * DH + (size_t)BATCH * DH
                            + (size_t)(bbase + bl) * DH + jbase + ul);
            } else if (t == S_LEN - 1) {
                __builtin_nontemporal_store(hv,
                    out + (size_t)S_LEN * BATCH * DH
                        + (size_t)(bbase + bl) * DH + jbase + ul);
            }

            __syncthreads();   // plds WAR before next iteration's writes
        }
    }
}

extern "C" void kernel_launch(void* const* d_in, const int* in_sizes, int n_in,
                              void* d_out, int out_size, void* d_ws, size_t ws_size,
                              hipStream_t stream) {
    const float* seq    = (const float*)d_in[0];
    const float* h_init = (const float*)d_in[1];
    const float* Wf     = (const float*)d_in[2];
    const float* Bf     = (const float*)d_in[3];
    const float* Wi     = (const float*)d_in[4];
    const float* Bi     = (const float*)d_in[5];
    const float* Wc     = (const float*)d_in[6];
    const float* Bc     = (const float*)d_in[7];
    const float* Wo     = (const float*)d_in[8];
    const float* Bo     = (const float*)d_in[9];
    float* out          = (float*)d_out;
    unsigned char* wsb  = (unsigned char*)d_ws;

    hipFuncSetAttribute((const void*)lstm_main,
                        hipFuncAttributeMaxDynamicSharedMemorySize, LDS_BYTES);

    hipLaunchKernelGGL(lstm_init, dim3(2048), dim3(THREADS), 0, stream,
                       seq, h_init, wsb);

    void* args[] = { (void*)&seq,
                     (void*)&Wf, (void*)&Bf,
                     (void*)&Wi, (void*)&Bi,
                     (void*)&Wc, (void*)&Bc,
                     (void*)&Wo, (void*)&Bo,
                     (void*)&out, (void*)&wsb };
    hipLaunchCooperativeKernel((void*)lstm_main, dim3(NWG), dim3(THREADS),
                               args, LDS_BYTES, stream);
}

// Round 18
// 2611.540 us; speedup vs baseline: 1.6479x; 1.6479x over previous
//
#include <hip/hip_runtime.h>
#include <hip/hip_bf16.h>

#define S_LEN   512
#define BATCH   64
#define DH      512
#define KDIM    1024      // 2*DH (concat [h, x])
#define NCOLS   64        // 4 gates * 16 units per WG
#define WGL     128       // WGs per layer
#define NWG     256
#define THREADS 256
#define NSLOT   4         // h rotation depth
#define FLAG_STRIDE 32    // uints: one flag per 128-B line
#define W_LDS_BYTES (NCOLS * KDIM * 2)           // 131072 weights
#define P_LDS_BYTES (16 * 64 * 16)               // 16384 partials
#define LDS_BYTES   (W_LDS_BYTES + P_LDS_BYTES)  // 147456 <= 160K

typedef __attribute__((ext_vector_type(8))) unsigned short u16x8;
typedef __attribute__((ext_vector_type(8))) __bf16         bf16x8;
typedef __attribute__((ext_vector_type(4))) float          f32x4;
typedef __attribute__((ext_vector_type(4))) unsigned       u32x4;

__device__ __forceinline__ unsigned short f2bf(float f) {
    unsigned u = __float_as_uint(f);
    return (unsigned short)((u + 0x7fffu + ((u >> 16) & 1u)) >> 16);   // RNE
}
__device__ __forceinline__ float sigmoid_f(float x) { return 1.f / (1.f + __expf(-x)); }
__device__ __forceinline__ float tanh_f(float x) {
    float e = __expf(2.f * x);
    return 1.f - 2.f / (e + 1.f);
}
__device__ __forceinline__ f32x4 mfma16(bf16x8 a, bf16x8 b, f32x4 c) {
    return __builtin_amdgcn_mfma_f32_16x16x32_bf16(a, b, c, 0, 0, 0);
}
// 32-bit agent-scope relaxed atomics (proven instruction class, compiler-tracked).
__device__ __forceinline__ unsigned ld_coh32(const unsigned* p) {
    return __hip_atomic_load(p, __ATOMIC_RELAXED, __HIP_MEMORY_SCOPE_AGENT);
}
__device__ __forceinline__ void st_coh32(unsigned* p, unsigned v) {
    __hip_atomic_store(p, v, __ATOMIC_RELAXED, __HIP_MEMORY_SCOPE_AGENT);
}

// ws layout (ushort idx unless noted):
//   0      : h0[4][64][512] bf16  (256 KB)  layer0 h rotation
//   131072 : h1[4][64][512] bf16  (256 KB)  layer1 h rotation
//   byte 524288 : flags[256 * 32] uint      per-WG flag, one per 128-B line
//   ushort 278528 : seq_bf16[512][64][512]  (32 MB) pre-converted x input
#define WS_H0    0
#define WS_H1    (NSLOT * BATCH * DH)
#define WS_BAR_B 524288
#define WS_XB    278528

__global__ void lstm_init(const float* __restrict__ seq,
                          const float* __restrict__ h_init,
                          unsigned short* __restrict__ ws) {
    const int gid = blockIdx.x * blockDim.x + threadIdx.x;
    unsigned* flags = (unsigned*)((char*)ws + WS_BAR_B);
    if (gid < NWG) flags[gid * FLAG_STRIDE] = 0;     // re-zeroed every launch
    if (gid < BATCH * DH) {
        ws[WS_H0 + gid] = f2bf(h_init[gid]);                                   // h0 slot0
        ws[WS_H1 + BATCH * DH + gid] = f2bf(h_init[(size_t)BATCH * DH + gid]); // h1 slot1
    }
    // seq fp32 -> bf16 pre-pass (4 elems/thread/iter, grid-stride)
    const size_t total = (size_t)S_LEN * BATCH * DH;           // 16M elems
    const size_t nthr  = (size_t)gridDim.x * blockDim.x;
    for (size_t i = (size_t)gid * 4; i < total; i += nthr * 4) {
        float4 v = *(const float4*)(seq + i);
        unsigned d0 = (unsigned)f2bf(v.x) | ((unsigned)f2bf(v.y) << 16);
        unsigned d1 = (unsigned)f2bf(v.z) | ((unsigned)f2bf(v.w) << 16);
        *(unsigned*)(ws + WS_XB + i)     = d0;
        *(unsigned*)(ws + WS_XB + i + 2) = d1;
    }
}

#define LDWB(off_) __builtin_bit_cast(bf16x8, *(const u16x8*)((const char*)wlds + (off_)))

__global__ __launch_bounds__(THREADS, 1)
void lstm_main(const float* __restrict__ seq,
               const float* __restrict__ Wf, const float* __restrict__ Bf,
               const float* __restrict__ Wi, const float* __restrict__ Bi,
               const float* __restrict__ Wc, const float* __restrict__ Bc,
               const float* __restrict__ Wo, const float* __restrict__ Bo,
               float* __restrict__ out, unsigned short* __restrict__ ws)
{
    extern __shared__ unsigned short wlds[];   // weights [64][1024] bf16 swizzled
    float* plds = (float*)((char*)wlds + W_LDS_BYTES);   // [16 frag][64 lane][4] f32

    const int wg    = blockIdx.x;
    const int layer = wg >> 7;               // 0..1
    const int rid   = wg & (WGL - 1);        // 0..127
    const int us    = rid >> 2;              // unit-slice 0..31
    const int bg    = rid & 3;               // batch-group 0..3
    const int jbase = us * 16;
    const int bbase = bg * 16;
    const int tid   = threadIdx.x;
    const int lane  = tid & 63;
    const int wave  = tid >> 6;

    unsigned short* h0b = ws + WS_H0;
    unsigned short* h1b = ws + WS_H1;
    unsigned* flags = (unsigned*)((char*)ws + WS_BAR_B);

    // ---- stage this WG's weight slice into LDS (bf16, swizzled), once ----
    {
        const size_t woff = (size_t)layer * KDIM * DH;
        const float* Wg[4] = { Wf + woff, Wi + woff, Wc + woff, Wo + woff };
        for (int idx = tid; idx < NCOLS * KDIM; idx += THREADS) {
            int mcol = idx & (NCOLS - 1);          // gate*16 + unit
            int k    = idx >> 6;
            float w  = Wg[mcol >> 4][(size_t)k * DH + jbase + (mcol & 15)];
            unsigned byte = ((unsigned)mcol * 2048u + (unsigned)k * 2u)
                          ^ (((unsigned)mcol & 7u) << 4);
            wlds[byte >> 1] = f2bf(w);
        }
    }

    // MFMA geometry: A=weights (M=16 units), B=acts (N=16 batch).
    // D (m89): col = lane&15 -> batch-local, row = (lane>>4)*4+r -> unit-local.
    const int ln  = lane & 15;
    const int lq  = lane >> 4;
    const int klo = lq * 8;
    const unsigned sw  = ((unsigned)(lane & 7)) << 4;
    const unsigned wbF = (0u * 16 + (unsigned)ln) * 2048u;
    const unsigned wbI = (1u * 16 + (unsigned)ln) * 2048u;
    const unsigned wbC = (2u * 16 + (unsigned)ln) * 2048u;
    const unsigned wbO = (3u * 16 + (unsigned)ln) * 2048u;

    // per-thread output cell: unit ul, batch bl  (256 threads = 16x16 cells)
    const int ul = tid & 15;
    const int bl = tid >> 4;
    const int lidx = (ul >> 2) * 16 + bl;    // source lane in D fragments
    const int ridx = ul & 3;                 // source reg in f32x4
    const float bF = Bf[layer * DH + jbase + ul];
    const float bI = Bi[layer * DH + jbase + ul];
    const float bC = Bc[layer * DH + jbase + ul];
    const float bO = Bo[layer * DH + jbase + ul];

    // ---- poll pointers ----
    // L0 (single poll B): lanes<8 self producers (need it); lanes 8..39 WAR vs
    //   32 L1 same-bg readers of h0 (need it-2); else idle.
    // L1: phase A = x-dep on 8 L0 producers (need it, ~1 period slack);
    //     phase B = h1 self-dep on 8 L1 producers (need it, tight).
    int flA = wg, flB = wg;
    if (!layer) {
        if (lane < 8)       flB = ((wave * 8 + lane) << 2) + bg;
        else if (lane < 40) flB = 128 + ((lane - 8) << 2) + bg;
    } else {
        if (lane >= 8 && lane < 16) flA = ((wave * 8 + (lane - 8)) << 2) + bg;
        if (lane < 8)               flB = 128 + ((wave * 8 + lane) << 2) + bg;
    }
    const unsigned* pfA = &flags[flA * FLAG_STRIDE];
    const unsigned* pfB = &flags[flB * FLAG_STRIDE];
    __syncthreads();

    float cs = 0.f;                          // cell state for (ul, bl)

    for (int it = 0; it <= S_LEN; ++it) {
        const bool active = layer ? (it >= 1) : (it < S_LEN);
        const int  t      = layer ? it - 1 : it;
        float hv = 0.f;

        if (active) {
            const int par = it & (NSLOT - 1);
            f32x4 eF = {0,0,0,0}, eI = {0,0,0,0}, eC = {0,0,0,0}, eO = {0,0,0,0};
            f32x4 oF = {0,0,0,0}, oI = {0,0,0,0}, oC = {0,0,0,0}, oO = {0,0,0,0};

            // ---- h-weight fragments preloaded (off the gated path) ----
            bf16x8 whF[4], whI[4], whC[4], whO[4];
            #pragma unroll
            for (int c = 0; c < 4; ++c) {
                const unsigned kb = ((unsigned)(wave * 4 + c) * 64u
                                     + (unsigned)klo * 2u) ^ sw;
                whF[c] = LDWB(wbF + kb); whI[c] = LDWB(wbI + kb);
                whC[c] = LDWB(wbC + kb); whO[c] = LDWB(wbO + kb);
            }

            unsigned ah[16];

            if (!layer) {
                // ---- x-half entirely pre-poll (seq_bf16, cached, flag-free) ----
                const unsigned short* xb = ws + WS_XB
                    + ((size_t)t * BATCH + bbase + ln) * DH + klo;
                #pragma unroll
                for (int c = 0; c < 4; ++c) {
                    u16x8 xv = *(const u16x8*)(xb + (wave * 4 + c) * 32);
                    bf16x8 av = __builtin_bit_cast(bf16x8, xv);
                    const unsigned kb = ((unsigned)(16 + wave * 4 + c) * 64u
                                         + (unsigned)klo * 2u) ^ sw;
                    bf16x8 wFx = LDWB(wbF + kb), wIx = LDWB(wbI + kb);
                    bf16x8 wCx = LDWB(wbC + kb), wOx = LDWB(wbO + kb);
                    if (c & 1) {
                        oF = mfma16(wFx, av, oF); oI = mfma16(wIx, av, oI);
                        oC = mfma16(wCx, av, oC); oO = mfma16(wOx, av, oO);
                    } else {
                        eF = mfma16(wFx, av, eF); eI = mfma16(wIx, av, eI);
                        eC = mfma16(wCx, av, eC); eO = mfma16(wOx, av, eO);
                    }
                }
                // ---- tight poll (self h-dep + WAR) ----
                {
                    int ni = (lane < 8) ? it : ((lane < 40) ? it - 2 : 0);
                    if (ni < 0) ni = 0;
                    const unsigned need = (unsigned)ni;
                    unsigned v = ld_coh32(pfB);
                    while (!__all((int)(v >= need)))
                        v = ld_coh32(pfB);
                }
                __builtin_amdgcn_sched_barrier(0);
                // ---- gated region: 16 coherent dwords + 4 MFMAs ----
                const unsigned* hp = (const unsigned*)
                    (h0b + (size_t)par * BATCH * DH + (size_t)(bbase + ln) * DH)
                    + wave * 64 + klo / 2;
                #pragma unroll
                for (int c = 0; c < 4; ++c)
                    #pragma unroll
                    for (int d = 0; d < 4; ++d)
                        ah[c * 4 + d] = ld_coh32(hp + c * 16 + d);
            } else {
                // ---- phase A: x-dep (slack ~1 period; instant steady-state) ----
                {
                    const unsigned need = (lane >= 8 && lane < 16) ? (unsigned)it : 0u;
                    unsigned v = ld_coh32(pfA);
                    while (!__all((int)(v >= need)))
                        v = ld_coh32(pfA);
                }
                __builtin_amdgcn_sched_barrier(0);
                // issue x loads (h0) -> flight overlaps phase B poll
                unsigned ax[16];
                const unsigned* xp = (const unsigned*)
                    (h0b + (size_t)par * BATCH * DH + (size_t)(bbase + ln) * DH)
                    + wave * 64 + klo / 2;
                #pragma unroll
                for (int c = 0; c < 4; ++c)
                    #pragma unroll
                    for (int d = 0; d < 4; ++d)
                        ax[c * 4 + d] = ld_coh32(xp + c * 16 + d);
                // ---- phase B: tight h1 self-dep ----
                {
                    const unsigned need = (lane < 8)
                        ? (unsigned)((it <= 1) ? 0 : it) : 0u;
                    unsigned v = ld_coh32(pfB);
                    while (!__all((int)(v >= need)))
                        v = ld_coh32(pfB);
                }
                __builtin_amdgcn_sched_barrier(0);
                // issue h loads -> flight overlaps x-MFMAs
                const unsigned* hp = (const unsigned*)
                    (h1b + (size_t)par * BATCH * DH + (size_t)(bbase + ln) * DH)
                    + wave * 64 + klo / 2;
                #pragma unroll
                for (int c = 0; c < 4; ++c)
                    #pragma unroll
                    for (int d = 0; d < 4; ++d)
                        ah[c * 4 + d] = ld_coh32(hp + c * 16 + d);
                // x-MFMAs (consume ax; h loads in flight)
                #pragma unroll
                for (int c = 0; c < 4; ++c) {
                    u32x4 q = { ax[c*4], ax[c*4+1], ax[c*4+2], ax[c*4+3] };
                    bf16x8 av = __builtin_bit_cast(bf16x8, q);
                    const unsigned kb = ((unsigned)(16 + wave * 4 + c) * 64u
                                         + (unsigned)klo * 2u) ^ sw;
                    bf16x8 wFx = LDWB(wbF + kb), wIx = LDWB(wbI + kb);
                    bf16x8 wCx = LDWB(wbC + kb), wOx = LDWB(wbO + kb);
                    if (c & 1) {
                        oF = mfma16(wFx, av, oF); oI = mfma16(wIx, av, oI);
                        oC = mfma16(wCx, av, oC); oO = mfma16(wOx, av, oO);
                    } else {
                        eF = mfma16(wFx, av, eF); eI = mfma16(wIx, av, eI);
                        eC = mfma16(wCx, av, eC); eO = mfma16(wOx, av, eO);
                    }
                }
            }

            // ---- h-MFMAs with preloaded weight fragments ----
            #pragma unroll
            for (int c = 0; c < 4; ++c) {
                u32x4 q = { ah[c*4], ah[c*4+1], ah[c*4+2], ah[c*4+3] };
                bf16x8 av = __builtin_bit_cast(bf16x8, q);
                if (c & 1) {
                    oF = mfma16(whF[c], av, oF); oI = mfma16(whI[c], av, oI);
                    oC = mfma16(whC[c], av, oC); oO = mfma16(whO[c], av, oO);
                } else {
                    eF = mfma16(whF[c], av, eF); eI = mfma16(whI[c], av, eI);
                    eC = mfma16(whC[c], av, eC); eO = mfma16(whO[c], av, eO);
                }
            }
            f32x4 pF = eF + oF, pI = eI + oI, pC = eC + oC, pO = eO + oO;

            // ---- cross-wave K-reduction via LDS (join point of all waves) ----
            f32x4* pv = (f32x4*)plds;
            pv[(wave * 4 + 0) * 64 + lane] = pF;
            pv[(wave * 4 + 1) * 64 + lane] = pI;
            pv[(wave * 4 + 2) * 64 + lane] = pC;
            pv[(wave * 4 + 3) * 64 + lane] = pO;
            __syncthreads();

            float sF = 0.f, sI = 0.f, sC = 0.f, sO = 0.f;
            #pragma unroll
            for (int w = 0; w < 4; ++w) {
                sF += plds[((w * 4 + 0) * 64 + lidx) * 4 + ridx];
                sI += plds[((w * 4 + 1) * 64 + lidx) * 4 + ridx];
                sC += plds[((w * 4 + 2) * 64 + lidx) * 4 + ridx];
                sO += plds[((w * 4 + 3) * 64 + lidx) * 4 + ridx];
            }

            const float fg = sigmoid_f(sF + bF);
            const float ig = sigmoid_f(sI + bI);
            const float ct = tanh_f  (sC + bC);
            const float og = sigmoid_f(sO + bO);
            const float cn = fg * cs + ig * ct;
            cs = cn;
            hv = og * tanh_f(cn);

            // ---- h-store: pack unit pairs, write-through (single destination) ----
            const unsigned hb16  = (unsigned)f2bf(hv);
            const unsigned other = (unsigned)__shfl_xor((int)hb16, 1, 64);
            const int npar = (it + 1) & (NSLOT - 1);
            if (!(ul & 1)) {
                unsigned dw = hb16 | (other << 16);
                unsigned short* dst = (layer ? h1b : h0b)
                    + (size_t)npar * BATCH * DH + (size_t)(bbase + bl) * DH + jbase + ul;
                st_coh32((unsigned*)dst, dw);
            }

            // ---- publish EARLY (h-stores drained by syncthreads), out after ----
            __syncthreads();
            if (tid == 0)
                st_coh32(&flags[wg * FLAG_STRIDE], (unsigned)(it + 1));

            if (layer) {
                __builtin_nontemporal_store(hv,
                    out + ((size_t)t * BATCH + bbase + bl) * DH + jbase + ul);
                if (t == S_LEN - 1)
                    __builtin_nontemporal_store(hv,
                        out + (size_t)S_LEN * BATCH * DH + (size_t)BATCH * DH
                            + (size_t)(bbase + bl) * DH + jbase + ul);
            } else if (t == S_LEN - 1) {
                __builtin_nontemporal_store(hv,
                    out + (size_t)S_LEN * BATCH * DH
                        + (size_t)(bbase + bl) * DH + jbase + ul);
            }
        }
    }
}

extern "C" void kernel_launch(void* const* d_in, const int* in_sizes, int n_in,
                              void* d_out, int out_size, void* d_ws, size_t ws_size,
                              hipStream_t stream) {
    const float* seq    = (const float*)d_in[0];
    const float* h_init = (const float*)d_in[1];
    const float* Wf     = (const float*)d_in[2];
    const float* Bf     = (const float*)d_in[3];
    const float* Wi     = (const float*)d_in[4];
    const float* Bi     = (const float*)d_in[5];
    const float* Wc     = (const float*)d_in[6];
    const float* Bc     = (const float*)d_in[7];
    const float* Wo     = (const float*)d_in[8];
    const float* Bo     = (const float*)d_in[9];
    float* out          = (float*)d_out;
    unsigned short* ws  = (unsigned short*)d_ws;

    hipFuncSetAttribute((const void*)lstm_main,
                        hipFuncAttributeMaxDynamicSharedMemorySize, LDS_BYTES);

    hipLaunchKernelGGL(lstm_init, dim3(2048), dim3(THREADS), 0, stream,
                       seq, h_init, ws);

    void* args[] = { (void*)&seq,
                     (void*)&Wf, (void*)&Bf,
                     (void*)&Wi, (void*)&Bi,
                     (void*)&Wc, (void*)&Bc,
                     (void*)&Wo, (void*)&Bo,
                     (void*)&out, (void*)&ws };
    hipLaunchCooperativeKernel((void*)lstm_main, dim3(NWG), dim3(THREADS),
                               args, LDS_BYTES, stream);
}

// Round 19
// 2549.975 us; speedup vs baseline: 1.6877x; 1.0241x over previous
//
#include <hip/hip_runtime.h>
#include <hip/hip_bf16.h>

#define S_LEN   512
#define BATCH   64
#define DH      512
#define KDIM    1024      // 2*DH (concat [h, x])
#define NCOLS   64        // 4 gates * 16 units per WG
#define WGL     128       // WGs per layer
#define NWG     256
#define THREADS 256
#define NSLOT   4         // h rotation depth
#define FLAG_STRIDE 32    // uints: one flag per 128-B line
#define W_LDS_BYTES (NCOLS * KDIM * 2)           // 131072 weights
#define P_LDS_BYTES (16 * 64 * 16)               // 16384 partials
#define LDS_BYTES   (W_LDS_BYTES + P_LDS_BYTES)  // 147456 <= 160K

typedef __attribute__((ext_vector_type(8))) unsigned short u16x8;
typedef __attribute__((ext_vector_type(8))) __bf16         bf16x8;
typedef __attribute__((ext_vector_type(4))) float          f32x4;
typedef __attribute__((ext_vector_type(4))) unsigned       u32x4;

__device__ __forceinline__ unsigned short f2bf(float f) {
    unsigned u = __float_as_uint(f);
    return (unsigned short)((u + 0x7fffu + ((u >> 16) & 1u)) >> 16);   // RNE
}
__device__ __forceinline__ float sigmoid_f(float x) { return 1.f / (1.f + __expf(-x)); }
__device__ __forceinline__ float tanh_f(float x) {
    float e = __expf(2.f * x);
    return 1.f - 2.f / (e + 1.f);
}
__device__ __forceinline__ f32x4 mfma16(bf16x8 a, bf16x8 b, f32x4 c) {
    return __builtin_amdgcn_mfma_f32_16x16x32_bf16(a, b, c, 0, 0, 0);
}
// 32-bit agent-scope relaxed atomics (proven instruction class, compiler-tracked).
__device__ __forceinline__ unsigned ld_coh32(const unsigned* p) {
    return __hip_atomic_load(p, __ATOMIC_RELAXED, __HIP_MEMORY_SCOPE_AGENT);
}
__device__ __forceinline__ void st_coh32(unsigned* p, unsigned v) {
    __hip_atomic_store(p, v, __ATOMIC_RELAXED, __HIP_MEMORY_SCOPE_AGENT);
}

// ws layout (ushort idx unless noted):
//   0      : h0[4][64][512] bf16  (256 KB)  layer0 h rotation
//   131072 : h1[4][64][512] bf16  (256 KB)  layer1 h rotation
//   byte 524288 : flags[256 * 32] uint      per-WG flag, one per 128-B line
//   ushort 278528 : seq_bf16[512][64][512]  (32 MB) pre-converted x input
#define WS_H0    0
#define WS_H1    (NSLOT * BATCH * DH)
#define WS_BAR_B 524288
#define WS_XB    278528

__global__ void lstm_init(const float* __restrict__ seq,
                          const float* __restrict__ h_init,
                          unsigned short* __restrict__ ws) {
    const int gid = blockIdx.x * blockDim.x + threadIdx.x;
    unsigned* flags = (unsigned*)((char*)ws + WS_BAR_B);
    if (gid < NWG) flags[gid * FLAG_STRIDE] = 0;     // re-zeroed every launch
    if (gid < BATCH * DH) {
        ws[WS_H0 + gid] = f2bf(h_init[gid]);                                   // h0 slot0
        ws[WS_H1 + BATCH * DH + gid] = f2bf(h_init[(size_t)BATCH * DH + gid]); // h1 slot1
    }
    // seq fp32 -> bf16 pre-pass (4 elems/thread/iter, grid-stride)
    const size_t total = (size_t)S_LEN * BATCH * DH;           // 16M elems
    const size_t nthr  = (size_t)gridDim.x * blockDim.x;
    for (size_t i = (size_t)gid * 4; i < total; i += nthr * 4) {
        float4 v = *(const float4*)(seq + i);
        unsigned d0 = (unsigned)f2bf(v.x) | ((unsigned)f2bf(v.y) << 16);
        unsigned d1 = (unsigned)f2bf(v.z) | ((unsigned)f2bf(v.w) << 16);
        *(unsigned*)(ws + WS_XB + i)     = d0;
        *(unsigned*)(ws + WS_XB + i + 2) = d1;
    }
}

#define LDWB(off_) __builtin_bit_cast(bf16x8, *(const u16x8*)((const char*)wlds + (off_)))

__global__ __launch_bounds__(THREADS, 1)
void lstm_main(const float* __restrict__ seq,
               const float* __restrict__ Wf, const float* __restrict__ Bf,
               const float* __restrict__ Wi, const float* __restrict__ Bi,
               const float* __restrict__ Wc, const float* __restrict__ Bc,
               const float* __restrict__ Wo, const float* __restrict__ Bo,
               float* __restrict__ out, unsigned short* __restrict__ ws)
{
    extern __shared__ unsigned short wlds[];   // weights [64][1024] bf16 swizzled
    float* plds = (float*)((char*)wlds + W_LDS_BYTES);   // partials, transposed layout

    const int wg    = blockIdx.x;
    const int layer = wg >> 7;               // 0..1
    const int rid   = wg & (WGL - 1);        // 0..127
    const int us    = rid >> 2;              // unit-slice 0..31
    const int bg    = rid & 3;               // batch-group 0..3
    const int jbase = us * 16;
    const int bbase = bg * 16;
    const int tid   = threadIdx.x;
    const int lane  = tid & 63;
    const int wave  = tid >> 6;

    unsigned short* h0b = ws + WS_H0;
    unsigned short* h1b = ws + WS_H1;
    unsigned* flags = (unsigned*)((char*)ws + WS_BAR_B);

    // ---- stage this WG's weight slice into LDS (bf16, swizzled), once ----
    {
        const size_t woff = (size_t)layer * KDIM * DH;
        const float* Wg[4] = { Wf + woff, Wi + woff, Wc + woff, Wo + woff };
        for (int idx = tid; idx < NCOLS * KDIM; idx += THREADS) {
            int mcol = idx & (NCOLS - 1);          // gate*16 + unit
            int k    = idx >> 6;
            float w  = Wg[mcol >> 4][(size_t)k * DH + jbase + (mcol & 15)];
            unsigned byte = ((unsigned)mcol * 2048u + (unsigned)k * 2u)
                          ^ (((unsigned)mcol & 7u) << 4);
            wlds[byte >> 1] = f2bf(w);
        }
    }

    // MFMA geometry: A=weights (M=16 units), B=acts (N=16 batch).
    // D (m89): col = lane&15 -> batch-local, row = (lane>>4)*4+r -> unit-local.
    const int ln  = lane & 15;
    const int lq  = lane >> 4;
    const int klo = lq * 8;
    const unsigned sw  = ((unsigned)(lane & 7)) << 4;
    const unsigned wbF = (0u * 16 + (unsigned)ln) * 2048u;
    const unsigned wbI = (1u * 16 + (unsigned)ln) * 2048u;
    const unsigned wbC = (2u * 16 + (unsigned)ln) * 2048u;
    const unsigned wbO = (3u * 16 + (unsigned)ln) * 2048u;

    // per-thread output cell: unit ul, batch bl  (256 threads = 16x16 cells)
    const int ul = tid & 15;
    const int bl = tid >> 4;
    const float bF = Bf[layer * DH + jbase + ul];
    const float bI = Bi[layer * DH + jbase + ul];
    const float bC = Bc[layer * DH + jbase + ul];
    const float bO = Bo[layer * DH + jbase + ul];

    // Transposed-partials indices (conflict-free LDS):
    //   writer lane L stores frag f at f32x4 slot [f*64 + (L&15)*4 + (L>>4)]
    //   reader thread reads float  [f*256 + bl*16 + (ul>>2)*4 + (ul&3)]
    const int wslot = (lane & 15) * 4 + (lane >> 4);
    const int rbase = bl * 16 + (ul >> 2) * 4 + (ul & 3);

    // ---- poll pointers (unchanged protocol) ----
    int flA = wg, flB = wg;
    if (!layer) {
        if (lane < 8)       flB = ((wave * 8 + lane) << 2) + bg;
        else if (lane < 40) flB = 128 + ((lane - 8) << 2) + bg;
    } else {
        if (lane >= 8 && lane < 16) flA = ((wave * 8 + (lane - 8)) << 2) + bg;
        if (lane < 8)               flB = 128 + ((wave * 8 + lane) << 2) + bg;
    }
    const unsigned* pfA = &flags[flA * FLAG_STRIDE];
    const unsigned* pfB = &flags[flB * FLAG_STRIDE];
    __syncthreads();

    float cs = 0.f;                          // cell state for (ul, bl)

    for (int it = 0; it <= S_LEN; ++it) {
        const bool active = layer ? (it >= 1) : (it < S_LEN);
        const int  t      = layer ? it - 1 : it;
        float hv = 0.f;

        if (active) {
            const int par = it & (NSLOT - 1);
            f32x4 eF = {0,0,0,0}, eI = {0,0,0,0}, eC = {0,0,0,0}, eO = {0,0,0,0};
            f32x4 oF = {0,0,0,0}, oI = {0,0,0,0}, oC = {0,0,0,0}, oO = {0,0,0,0};

            unsigned ah[16];

            #define XMFMA(c_, av_) do {                                            \
                const unsigned kb = ((unsigned)(16 + wave * 4 + (c_)) * 64u        \
                                     + (unsigned)klo * 2u) ^ sw;                   \
                bf16x8 wFx = LDWB(wbF + kb), wIx = LDWB(wbI + kb);                 \
                bf16x8 wCx = LDWB(wbC + kb), wOx = LDWB(wbO + kb);                 \
                if ((c_) & 1) {                                                    \
                    oF = mfma16(wFx, (av_), oF); oI = mfma16(wIx, (av_), oI);      \
                    oC = mfma16(wCx, (av_), oC); oO = mfma16(wOx, (av_), oO);      \
                } else {                                                           \
                    eF = mfma16(wFx, (av_), eF); eI = mfma16(wIx, (av_), eI);      \
                    eC = mfma16(wCx, (av_), eC); eO = mfma16(wOx, (av_), eO);      \
                } } while (0)

            if (!layer) {
                // ---- tight poll FIRST (self h-dep + WAR) ----
                {
                    int ni = (lane < 8) ? it : ((lane < 40) ? it - 2 : 0);
                    if (ni < 0) ni = 0;
                    const unsigned need = (unsigned)ni;
                    unsigned v = ld_coh32(pfB);
                    while (!__all((int)(v >= need)))
                        v = ld_coh32(pfB);
                }
                __builtin_amdgcn_sched_barrier(0);
                // ---- issue gated h loads immediately (flight overlaps x-half) ----
                const unsigned* hp = (const unsigned*)
                    (h0b + (size_t)par * BATCH * DH + (size_t)(bbase + ln) * DH)
                    + wave * 64 + klo / 2;
                #pragma unroll
                for (int c = 0; c < 4; ++c)
                    #pragma unroll
                    for (int d = 0; d < 4; ++d)
                        ah[c * 4 + d] = ld_coh32(hp + c * 16 + d);
                __builtin_amdgcn_sched_barrier(0);
                // ---- x-half (cached seq_bf16) under the h-load flight ----
                const unsigned short* xb = ws + WS_XB
                    + ((size_t)t * BATCH + bbase + ln) * DH + klo;
                #pragma unroll
                for (int c = 0; c < 4; ++c) {
                    u16x8 xv = *(const u16x8*)(xb + (wave * 4 + c) * 32);
                    bf16x8 av = __builtin_bit_cast(bf16x8, xv);
                    XMFMA(c, av);
                }
            } else {
                // ---- phase A: x-dep (slack ~1 period; instant steady-state) ----
                {
                    const unsigned need = (lane >= 8 && lane < 16) ? (unsigned)it : 0u;
                    unsigned v = ld_coh32(pfA);
                    while (!__all((int)(v >= need)))
                        v = ld_coh32(pfA);
                }
                __builtin_amdgcn_sched_barrier(0);
                // issue x loads (h0) -> flight overlaps phase B poll
                unsigned ax[16];
                const unsigned* xp = (const unsigned*)
                    (h0b + (size_t)par * BATCH * DH + (size_t)(bbase + ln) * DH)
                    + wave * 64 + klo / 2;
                #pragma unroll
                for (int c = 0; c < 4; ++c)
                    #pragma unroll
                    for (int d = 0; d < 4; ++d)
                        ax[c * 4 + d] = ld_coh32(xp + c * 16 + d);
                // ---- phase B: tight h1 self-dep ----
                {
                    const unsigned need = (lane < 8)
                        ? (unsigned)((it <= 1) ? 0 : it) : 0u;
                    unsigned v = ld_coh32(pfB);
                    while (!__all((int)(v >= need)))
                        v = ld_coh32(pfB);
                }
                __builtin_amdgcn_sched_barrier(0);
                // issue h loads -> flight overlaps x-MFMAs
                const unsigned* hp = (const unsigned*)
                    (h1b + (size_t)par * BATCH * DH + (size_t)(bbase + ln) * DH)
                    + wave * 64 + klo / 2;
                #pragma unroll
                for (int c = 0; c < 4; ++c)
                    #pragma unroll
                    for (int d = 0; d < 4; ++d)
                        ah[c * 4 + d] = ld_coh32(hp + c * 16 + d);
                // x-MFMAs (consume ax; h loads in flight)
                #pragma unroll
                for (int c = 0; c < 4; ++c) {
                    u32x4 q = { ax[c*4], ax[c*4+1], ax[c*4+2], ax[c*4+3] };
                    bf16x8 av = __builtin_bit_cast(bf16x8, q);
                    XMFMA(c, av);
                }
            }
            #undef XMFMA

            // ---- h-weight fragments (LDS reads overlap remaining h flight) ----
            bf16x8 whF[4], whI[4], whC[4], whO[4];
            #pragma unroll
            for (int c = 0; c < 4; ++c) {
                const unsigned kb = ((unsigned)(wave * 4 + c) * 64u
                                     + (unsigned)klo * 2u) ^ sw;
                whF[c] = LDWB(wbF + kb); whI[c] = LDWB(wbI + kb);
                whC[c] = LDWB(wbC + kb); whO[c] = LDWB(wbO + kb);
            }

            // ---- h-MFMAs ----
            #pragma unroll
            for (int c = 0; c < 4; ++c) {
                u32x4 q = { ah[c*4], ah[c*4+1], ah[c*4+2], ah[c*4+3] };
                bf16x8 av = __builtin_bit_cast(bf16x8, q);
                if (c & 1) {
                    oF = mfma16(whF[c], av, oF); oI = mfma16(whI[c], av, oI);
                    oC = mfma16(whC[c], av, oC); oO = mfma16(whO[c], av, oO);
                } else {
                    eF = mfma16(whF[c], av, eF); eI = mfma16(whI[c], av, eI);
                    eC = mfma16(whC[c], av, eC); eO = mfma16(whO[c], av, eO);
                }
            }
            f32x4 pF = eF + oF, pI = eI + oI, pC = eC + oC, pO = eO + oO;

            // ---- cross-wave K-reduction via LDS (transposed, conflict-free) ----
            f32x4* pv = (f32x4*)plds;
            pv[(wave * 4 + 0) * 64 + wslot] = pF;
            pv[(wave * 4 + 1) * 64 + wslot] = pI;
            pv[(wave * 4 + 2) * 64 + wslot] = pC;
            pv[(wave * 4 + 3) * 64 + wslot] = pO;
            __syncthreads();

            float sF = 0.f, sI = 0.f, sC = 0.f, sO = 0.f;
            #pragma unroll
            for (int w = 0; w < 4; ++w) {
                sF += plds[(w * 4 + 0) * 256 + rbase];
                sI += plds[(w * 4 + 1) * 256 + rbase];
                sC += plds[(w * 4 + 2) * 256 + rbase];
                sO += plds[(w * 4 + 3) * 256 + rbase];
            }

            const float fg = sigmoid_f(sF + bF);
            const float ig = sigmoid_f(sI + bI);
            const float ct = tanh_f  (sC + bC);
            const float og = sigmoid_f(sO + bO);
            const float cn = fg * cs + ig * ct;
            cs = cn;
            hv = og * tanh_f(cn);

            // ---- h-store: pack unit pairs, write-through (single destination) ----
            const unsigned hb16  = (unsigned)f2bf(hv);
            const unsigned other = (unsigned)__shfl_xor((int)hb16, 1, 64);
            const int npar = (it + 1) & (NSLOT - 1);
            if (!(ul & 1)) {
                unsigned dw = hb16 | (other << 16);
                unsigned short* dst = (layer ? h1b : h0b)
                    + (size_t)npar * BATCH * DH + (size_t)(bbase + bl) * DH + jbase + ul;
                st_coh32((unsigned*)dst, dw);
            }

            // ---- publish EARLY (h-stores drained by syncthreads), out after ----
            __syncthreads();
            if (tid == 0)
                st_coh32(&flags[wg * FLAG_STRIDE], (unsigned)(it + 1));

            if (layer) {
                __builtin_nontemporal_store(hv,
                    out + ((size_t)t * BATCH + bbase + bl) * DH + jbase + ul);
                if (t == S_LEN - 1)
                    __builtin_nontemporal_store(hv,
                        out + (size_t)S_LEN * BATCH * DH + (size_t)BATCH * DH
                            + (size_t)(bbase + bl) * DH + jbase + ul);
            } else if (t == S_LEN - 1) {
                __builtin_nontemporal_store(hv,
                    out + (size_t)S_LEN * BATCH * DH
                        + (size_t)(bbase + bl) * DH + jbase + ul);
            }
        }
    }
}

extern "C" void kernel_launch(void* const* d_in, const int* in_sizes, int n_in,
                              void* d_out, int out_size, void* d_ws, size_t ws_size,
                              hipStream_t stream) {
    const float* seq    = (const float*)d_in[0];
    const float* h_init = (const float*)d_in[1];
    const float* Wf     = (const float*)d_in[2];
    const float* Bf     = (const float*)d_in[3];
    const float* Wi     = (const float*)d_in[4];
    const float* Bi     = (const float*)d_in[5];
    const float* Wc     = (const float*)d_in[6];
    const float* Bc     = (const float*)d_in[7];
    const float* Wo     = (const float*)d_in[8];
    const float* Bo     = (const float*)d_in[9];
    float* out          = (float*)d_out;
    unsigned short* ws  = (unsigned short*)d_ws;

    hipFuncSetAttribute((const void*)lstm_main,
                        hipFuncAttributeMaxDynamicSharedMemorySize, LDS_BYTES);

    hipLaunchKernelGGL(lstm_init, dim3(2048), dim3(THREADS), 0, stream,
                       seq, h_init, ws);

    void* args[] = { (void*)&seq,
                     (void*)&Wf, (void*)&Bf,
                     (void*)&Wi, (void*)&Bi,
                     (void*)&Wc, (void*)&Bc,
                     (void*)&Wo, (void*)&Bo,
                     (void*)&out, (void*)&ws };
    hipLaunchCooperativeKernel((void*)lstm_main, dim3(NWG), dim3(THREADS),
                               args, LDS_BYTES, stream);
}